// Round 1
// baseline (1587.358 us; speedup 1.0000x reference)
//
#include <hip/hip_runtime.h>

// GCN 2-layer, restructured so all edge aggregation happens on 2-wide features:
//   a = A_hat x            (edge atomics, 2 floats/edge)
//   h = relu(a W1 + b1)    (registers only, 16-wide)
//   g = h W2               (2-wide)
//   out = A_hat g + b2     (edge atomics, 2 floats/edge)
// deg/dinv computed once (same adjacency both layers). Self-loop terms folded
// into the pointwise MLP kernel.

__global__ void deg_kernel(const int* __restrict__ dst, float* __restrict__ deg, int E) {
    int i = blockIdx.x * blockDim.x + threadIdx.x;
    int stride = gridDim.x * blockDim.x;
    for (; i < E; i += stride) {
        unsafeAtomicAdd(&deg[dst[i]], 1.0f);
    }
}

__global__ void dinv_kernel(float* __restrict__ deg, int N) {
    int i = blockIdx.x * blockDim.x + threadIdx.x;
    if (i < N) deg[i] = rsqrtf(deg[i] + 1.0f);  // +1 = self-loop; always > 0
}

__global__ void agg_kernel(const int* __restrict__ src, const int* __restrict__ dst,
                           const float* __restrict__ dinv,
                           const float2* __restrict__ feat,
                           float* __restrict__ out, int E) {
    int i = blockIdx.x * blockDim.x + threadIdx.x;
    int stride = gridDim.x * blockDim.x;
    for (; i < E; i += stride) {
        int s = src[i];
        int d = dst[i];
        float w = dinv[s] * dinv[d];
        float2 v = feat[s];
        unsafeAtomicAdd(&out[2 * d],     v.x * w);
        unsafeAtomicAdd(&out[2 * d + 1], v.y * w);
    }
}

__global__ void mlp_kernel(const float2* __restrict__ x, const float* __restrict__ dinv,
                           const float2* __restrict__ a,
                           const float* __restrict__ W1, const float* __restrict__ b1,
                           const float* __restrict__ W2, const float* __restrict__ b2,
                           float2* __restrict__ g, float2* __restrict__ out, int N) {
    int i = blockIdx.x * blockDim.x + threadIdx.x;
    if (i >= N) return;
    float di = dinv[i];
    float d2 = di * di;
    float2 av = a[i];
    float2 xv = x[i];
    // self-loop contribution of layer-1 aggregation
    av.x = fmaf(xv.x, d2, av.x);
    av.y = fmaf(xv.y, d2, av.y);
    float g0 = 0.f, g1 = 0.f;
#pragma unroll
    for (int j = 0; j < 16; ++j) {
        float h = fmaf(av.x, W1[j], fmaf(av.y, W1[16 + j], b1[j]));
        h = fmaxf(h, 0.f);
        g0 = fmaf(h, W2[2 * j],     g0);
        g1 = fmaf(h, W2[2 * j + 1], g1);
    }
    g[i] = make_float2(g0, g1);
    // init output with bias + layer-2 self-loop term; edge atomics add the rest
    out[i] = make_float2(fmaf(g0, d2, b2[0]), fmaf(g1, d2, b2[1]));
}

extern "C" void kernel_launch(void* const* d_in, const int* in_sizes, int n_in,
                              void* d_out, int out_size, void* d_ws, size_t ws_size,
                              hipStream_t stream) {
    const float2* x  = (const float2*)d_in[0];
    const int*    ei = (const int*)d_in[1];   // [2, E] row-major: src then dst
    const float*  W1 = (const float*)d_in[2];
    const float*  b1 = (const float*)d_in[3];
    const float*  W2 = (const float*)d_in[4];
    const float*  b2 = (const float*)d_in[5];

    const int N = in_sizes[0] / 2;
    const int E = in_sizes[1] / 2;
    const int* src = ei;
    const int* dst = ei + E;

    float* ws  = (float*)d_ws;
    float* deg = ws;              // N floats (becomes dinv in place)
    float* a   = ws + N;          // 2N floats (layer-1 aggregate)
    float* g   = ws + 3 * (size_t)N;  // 2N floats (h @ W2)
    float* out = (float*)d_out;

    // zero deg + a (workspace is poisoned, and atomics accumulate into these)
    hipMemsetAsync(ws, 0, (size_t)3 * N * sizeof(float), stream);

    const int EB = 2048, TB = 256;
    const int NB = (N + TB - 1) / TB;

    deg_kernel<<<EB, TB, 0, stream>>>(dst, deg, E);
    dinv_kernel<<<NB, TB, 0, stream>>>(deg, N);
    agg_kernel<<<EB, TB, 0, stream>>>(src, dst, deg, x, a, E);
    mlp_kernel<<<NB, TB, 0, stream>>>(x, deg, (const float2*)a, W1, b1, W2, b2,
                                      (float2*)g, (float2*)out, N);
    agg_kernel<<<EB, TB, 0, stream>>>(src, dst, deg, (const float2*)g, out, E);
}

// Round 2
// 1576.729 us; speedup vs baseline: 1.0067x; 1.0067x over previous
//
#include <hip/hip_runtime.h>

// GCN 2-layer. All edge aggregation on 2-wide features (GCNConv is linear:
// aggregate narrow side). Atomics are XCD-LOCAL: 8 private accumulator copies
// indexed by HW_REG_XCC_ID; global_atomic_add_f32 with no sc bits executes in
// the local XCD's L2 (fast, cached) instead of the device-coherent EA path
// (which write-through'd 400 MB/dispatch in round 1). Copies are reduced in
// the following dispatch (kernel-end release flushes L2).
//
// Factored norm: a[d] = dinv[d] * sum_{s in N(d) u {d}} dinv[s]*x[s].

#define NXCD 8

__device__ __forceinline__ int xcd_id() {
    int x;
    asm volatile("s_getreg_b32 %0, hwreg(HW_REG_XCC_ID)" : "=s"(x));
    return x & (NXCD - 1);
}

// XCD-local (L2-resident) fp32 atomic add, no return, no sc bits.
__device__ __forceinline__ void l2_atomic_add(float* p, float v) {
    asm volatile("global_atomic_add_f32 %0, %1, off" :: "v"(p), "v"(v) : "memory");
}

__global__ void deg_kernel(const int* __restrict__ dst, float* __restrict__ deg8,
                           int E, int N) {
    float* mydeg = deg8 + (size_t)xcd_id() * N;
    int i = blockIdx.x * blockDim.x + threadIdx.x;
    int stride = gridDim.x * blockDim.x;
    for (; i < E; i += stride)
        l2_atomic_add(&mydeg[dst[i]], 1.0f);
}

__global__ void dinv_y_kernel(const float* __restrict__ deg8, const float2* __restrict__ x,
                              float* __restrict__ dinv, float2* __restrict__ y, int N) {
    int i = blockIdx.x * blockDim.x + threadIdx.x;
    if (i >= N) return;
    float s = 1.0f;  // self-loop
#pragma unroll
    for (int c = 0; c < NXCD; ++c) s += deg8[(size_t)c * N + i];
    float di = rsqrtf(s);
    dinv[i] = di;
    float2 xv = x[i];
    y[i] = make_float2(di * xv.x, di * xv.y);
}

__global__ void agg_kernel(const int* __restrict__ src, const int* __restrict__ dst,
                           const float2* __restrict__ feat, float* __restrict__ acc8,
                           int E, int N) {
    float* acc = acc8 + (size_t)xcd_id() * 2 * N;
    int i = blockIdx.x * blockDim.x + threadIdx.x;
    int stride = gridDim.x * blockDim.x;
    for (; i < E; i += stride) {
        int s = src[i], d = dst[i];
        float2 v = feat[s];
        l2_atomic_add(&acc[2 * d],     v.x);
        l2_atomic_add(&acc[2 * d + 1], v.y);
    }
}

// Reduce layer-1 partials, re-zero them for layer 2, run the 2->16->2 MLP,
// write g' = dinv * (h @ W2).
__global__ void mlp_kernel(const float* __restrict__ dinv, const float2* __restrict__ y,
                           float* __restrict__ acc8,
                           const float* __restrict__ W1, const float* __restrict__ b1,
                           const float* __restrict__ W2,
                           float2* __restrict__ gp, int N) {
    int i = blockIdx.x * blockDim.x + threadIdx.x;
    if (i >= N) return;
    float2 yv = y[i];
    float s0 = yv.x, s1 = yv.y;  // self-loop term
#pragma unroll
    for (int c = 0; c < NXCD; ++c) {
        float2* p = (float2*)(acc8 + (size_t)c * 2 * N) + i;
        float2 t = *p;
        s0 += t.x; s1 += t.y;
        *p = make_float2(0.f, 0.f);  // re-zero copies for the layer-2 pass
    }
    float di = dinv[i];
    float ax = di * s0, ay = di * s1;
    float g0 = 0.f, g1 = 0.f;
#pragma unroll
    for (int j = 0; j < 16; ++j) {
        float h = fmaf(ax, W1[j], fmaf(ay, W1[16 + j], b1[j]));
        h = fmaxf(h, 0.f);
        g0 = fmaf(h, W2[2 * j],     g0);
        g1 = fmaf(h, W2[2 * j + 1], g1);
    }
    gp[i] = make_float2(di * g0, di * g1);
}

__global__ void final_kernel(const float* __restrict__ dinv, const float2* __restrict__ gp,
                             const float* __restrict__ acc8, const float* __restrict__ b2,
                             float2* __restrict__ out, int N) {
    int i = blockIdx.x * blockDim.x + threadIdx.x;
    if (i >= N) return;
    float2 gv = gp[i];
    float s0 = gv.x, s1 = gv.y;  // layer-2 self-loop term (g'[i])
#pragma unroll
    for (int c = 0; c < NXCD; ++c) {
        const float2* p = (const float2*)(acc8 + (size_t)c * 2 * N) + i;
        float2 t = *p;
        s0 += t.x; s1 += t.y;
    }
    float di = dinv[i];
    out[i] = make_float2(fmaf(di, s0, b2[0]), fmaf(di, s1, b2[1]));
}

extern "C" void kernel_launch(void* const* d_in, const int* in_sizes, int n_in,
                              void* d_out, int out_size, void* d_ws, size_t ws_size,
                              hipStream_t stream) {
    const float2* x  = (const float2*)d_in[0];
    const int*    ei = (const int*)d_in[1];   // [2, E]: src row then dst row
    const float*  W1 = (const float*)d_in[2];
    const float*  b1 = (const float*)d_in[3];
    const float*  W2 = (const float*)d_in[4];
    const float*  b2 = (const float*)d_in[5];

    const int N = in_sizes[0] / 2;
    const int E = in_sizes[1] / 2;
    const int* src = ei;
    const int* dst = ei + E;

    float* ws   = (float*)d_ws;
    float* deg8 = ws;                       // 8N  (per-XCD degree partials)
    float* a8   = ws + 8 * (size_t)N;       // 16N (per-XCD 2-wide aggregates)
    float* dinv = ws + 24 * (size_t)N;      // N
    float* y    = ws + 25 * (size_t)N;      // 2N  (dinv * x)
    float* gp   = ws + 27 * (size_t)N;      // 2N  (dinv * (h@W2))
    float* out  = (float*)d_out;

    // zero deg8 + a8 (24N floats, contiguous)
    hipMemsetAsync(ws, 0, (size_t)24 * N * sizeof(float), stream);

    const int EB = 2048, TB = 256;
    const int NB = (N + TB - 1) / TB;

    deg_kernel  <<<EB, TB, 0, stream>>>(dst, deg8, E, N);
    dinv_y_kernel<<<NB, TB, 0, stream>>>(deg8, x, dinv, (float2*)y, N);
    agg_kernel  <<<EB, TB, 0, stream>>>(src, dst, (const float2*)y, a8, E, N);
    mlp_kernel  <<<NB, TB, 0, stream>>>(dinv, (const float2*)y, a8, W1, b1, W2,
                                        (float2*)gp, N);
    agg_kernel  <<<EB, TB, 0, stream>>>(src, dst, (const float2*)gp, a8, E, N);
    final_kernel<<<NB, TB, 0, stream>>>(dinv, (const float2*)gp, a8, b2,
                                        (float2*)out, N);
}

// Round 5
// 372.371 us; speedup vs baseline: 4.2628x; 4.2343x over previous
//
#include <hip/hip_runtime.h>

// GCN 2-layer, atomic-free aggregation.
//   Round-1/2 lesson: global fp32 atomics on gfx950 write through to EA
//   (~32 B/atomic, ~20 G/s) regardless of scope -> 624 us per edge pass.
// Plan: counting-sort edges by dst bucket (512 nodes/bucket) once, then each
// layer's aggregation is one WG per bucket accumulating into LDS (ds atomics),
// with coalesced loads of packed edges and L2-resident gathers of the 2-wide
// source features. GCNConv is linear -> aggregate on the 2-wide side only:
//   a = A_hat x ; h = relu(aW1+b1) ; gp = dinv*(h W2) ; out = A_hat-part(gp) + b2
// Self-loop terms folded into the epilogues (edge list has no self-loops).
// (Rounds 3-4 were infra failures at push time -- container never ran the
// code. Identical design resubmitted.)

typedef unsigned int u32;

#define BUCKET_BITS 9
#define BUCKET_SIZE (1 << BUCKET_BITS)   // 512 nodes per bucket
#define MAX_NBUCK 512                    // supports N <= 262144
#define SCATTER_CHUNK 4096

// ---- Phase A: counting sort of edges by dst bucket ----

__global__ void hist_kernel(const int* __restrict__ dst, u32* __restrict__ cnt,
                            int E, int nbuck) {
    __shared__ u32 h[MAX_NBUCK];
    int t = threadIdx.x;
    for (int j = t; j < nbuck; j += blockDim.x) h[j] = 0;
    __syncthreads();
    int i = blockIdx.x * blockDim.x + t;
    int stride = gridDim.x * blockDim.x;
    for (; i < E; i += stride) atomicAdd(&h[((u32)dst[i]) >> BUCKET_BITS], 1u);
    __syncthreads();
    for (int j = t; j < nbuck; j += blockDim.x)
        if (h[j]) atomicAdd(&cnt[j], h[j]);
}

__global__ void scan_kernel(const u32* __restrict__ cnt, u32* __restrict__ offsets,
                            u32* __restrict__ cursor, int nbuck) {
    __shared__ u32 s[MAX_NBUCK];
    int t = threadIdx.x;  // 512 threads
    u32 v = (t < nbuck) ? cnt[t] : 0u;
    s[t] = v;
    for (int o = 1; o < MAX_NBUCK; o <<= 1) {
        __syncthreads();
        u32 u = (t >= o) ? s[t - o] : 0u;
        __syncthreads();
        s[t] += u;
    }
    __syncthreads();
    if (t < nbuck) {
        u32 inc = s[t];
        offsets[t + 1] = inc;      // inclusive
        cursor[t] = inc - v;       // exclusive (scatter cursor)
    }
    if (t == 0) offsets[0] = 0;
}

__global__ void scatter_kernel(const int* __restrict__ src, const int* __restrict__ dst,
                               u32* __restrict__ cursor, u32* __restrict__ sorted,
                               int E, int nbuck) {
    __shared__ u32 hist[MAX_NBUCK];
    __shared__ u32 base[MAX_NBUCK];
    int t = threadIdx.x;  // 256
    for (int j = t; j < nbuck; j += blockDim.x) hist[j] = 0;
    __syncthreads();
    int start = blockIdx.x * SCATTER_CHUNK;
    int end = min(start + SCATTER_CHUNK, E);
    for (int i = start + t; i < end; i += blockDim.x)
        atomicAdd(&hist[((u32)dst[i]) >> BUCKET_BITS], 1u);
    __syncthreads();
    for (int j = t; j < nbuck; j += blockDim.x) {
        u32 c = hist[j];
        base[j] = c ? atomicAdd(&cursor[j], c) : 0u;  // one global atomic per (block,bucket)
    }
    __syncthreads();
    for (int j = t; j < nbuck; j += blockDim.x) hist[j] = 0;
    __syncthreads();
    for (int i = start + t; i < end; i += blockDim.x) {
        u32 d = (u32)dst[i];
        u32 b = d >> BUCKET_BITS;
        u32 pos = base[b] + atomicAdd(&hist[b], 1u);
        sorted[pos] = ((u32)src[i] << BUCKET_BITS) | (d & (BUCKET_SIZE - 1));
    }
}

// ---- Phase B: bucketed LDS aggregation ----

__global__ void deg_kernel(const u32* __restrict__ sorted, const u32* __restrict__ offsets,
                           float* __restrict__ deg, int N) {
    __shared__ float cnt[BUCKET_SIZE];
    int t = threadIdx.x;  // 512
    cnt[t] = 0.f;
    __syncthreads();
    int b = blockIdx.x;
    u32 e1 = offsets[b + 1];
    for (u32 i = offsets[b] + t; i < e1; i += blockDim.x)
        atomicAdd(&cnt[sorted[i] & (BUCKET_SIZE - 1)], 1.0f);
    __syncthreads();
    int node = (b << BUCKET_BITS) + t;
    if (node < N) deg[node] = cnt[t];
}

__global__ void dinv_y_kernel(float* __restrict__ deg /*in-place -> dinv*/,
                              const float2* __restrict__ x, float2* __restrict__ y, int N) {
    int i = blockIdx.x * blockDim.x + threadIdx.x;
    if (i >= N) return;
    float di = rsqrtf(deg[i] + 1.0f);  // +1 self-loop, always > 0
    deg[i] = di;
    float2 xv = x[i];
    y[i] = make_float2(di * xv.x, di * xv.y);
}

// a[d] = dinv[d] * (sum_{s->d} y[s] + y[d])
__global__ void agg1_kernel(const u32* __restrict__ sorted, const u32* __restrict__ offsets,
                            const float2* __restrict__ y, const float* __restrict__ dinv,
                            float2* __restrict__ a, int N) {
    __shared__ float accx[BUCKET_SIZE];
    __shared__ float accy[BUCKET_SIZE];
    int t = threadIdx.x;  // 512
    accx[t] = 0.f;
    accy[t] = 0.f;
    __syncthreads();
    int b = blockIdx.x;
    u32 e1 = offsets[b + 1];
#pragma unroll 4
    for (u32 i = offsets[b] + t; i < e1; i += blockDim.x) {
        u32 e = sorted[i];
        float2 v = y[e >> BUCKET_BITS];
        u32 ld = e & (BUCKET_SIZE - 1);
        atomicAdd(&accx[ld], v.x);
        atomicAdd(&accy[ld], v.y);
    }
    __syncthreads();
    int node = (b << BUCKET_BITS) + t;
    if (node < N) {
        float2 yv = y[node];
        float di = dinv[node];
        a[node] = make_float2(di * (accx[t] + yv.x), di * (accy[t] + yv.y));
    }
}

// h = relu(a W1 + b1); gp = dinv * (h W2)   (gp aliases the y buffer)
__global__ void mlp_kernel(const float* __restrict__ dinv, const float2* __restrict__ a,
                           const float* __restrict__ W1, const float* __restrict__ b1,
                           const float* __restrict__ W2, float2* __restrict__ gp, int N) {
    int i = blockIdx.x * blockDim.x + threadIdx.x;
    if (i >= N) return;
    float2 av = a[i];
    float g0 = 0.f, g1 = 0.f;
#pragma unroll
    for (int j = 0; j < 16; ++j) {
        float h = fmaf(av.x, W1[j], fmaf(av.y, W1[16 + j], b1[j]));
        h = fmaxf(h, 0.f);
        g0 = fmaf(h, W2[2 * j], g0);
        g1 = fmaf(h, W2[2 * j + 1], g1);
    }
    float di = dinv[i];
    gp[i] = make_float2(di * g0, di * g1);
}

// out[d] = dinv[d] * (sum_{s->d} gp[s] + gp[d]) + b2
__global__ void agg2_kernel(const u32* __restrict__ sorted, const u32* __restrict__ offsets,
                            const float2* __restrict__ gp, const float* __restrict__ dinv,
                            const float* __restrict__ b2, float2* __restrict__ out, int N) {
    __shared__ float accx[BUCKET_SIZE];
    __shared__ float accy[BUCKET_SIZE];
    int t = threadIdx.x;  // 512
    accx[t] = 0.f;
    accy[t] = 0.f;
    __syncthreads();
    int b = blockIdx.x;
    u32 e1 = offsets[b + 1];
#pragma unroll 4
    for (u32 i = offsets[b] + t; i < e1; i += blockDim.x) {
        u32 e = sorted[i];
        float2 v = gp[e >> BUCKET_BITS];
        u32 ld = e & (BUCKET_SIZE - 1);
        atomicAdd(&accx[ld], v.x);
        atomicAdd(&accy[ld], v.y);
    }
    __syncthreads();
    int node = (b << BUCKET_BITS) + t;
    if (node < N) {
        float2 gv = gp[node];
        float di = dinv[node];
        out[node] = make_float2(fmaf(di, accx[t] + gv.x, b2[0]),
                                fmaf(di, accy[t] + gv.y, b2[1]));
    }
}

extern "C" void kernel_launch(void* const* d_in, const int* in_sizes, int n_in,
                              void* d_out, int out_size, void* d_ws, size_t ws_size,
                              hipStream_t stream) {
    const float2* x  = (const float2*)d_in[0];
    const int*    ei = (const int*)d_in[1];   // [2, E]: src row then dst row
    const float*  W1 = (const float*)d_in[2];
    const float*  b1 = (const float*)d_in[3];
    const float*  W2 = (const float*)d_in[4];
    const float*  b2 = (const float*)d_in[5];

    const int N = in_sizes[0] / 2;
    const int E = in_sizes[1] / 2;
    const int* src = ei;
    const int* dst = ei + E;
    const int nbuck = (N + BUCKET_SIZE - 1) >> BUCKET_BITS;

    u32* cnt     = (u32*)d_ws;           // 512
    u32* offsets = cnt + MAX_NBUCK;      // 1024 (uses nbuck+1)
    u32* cursor  = cnt + 3 * MAX_NBUCK;  // 512
    u32* sorted  = cnt + 4 * MAX_NBUCK;  // E
    float* deg   = (float*)(sorted + E); // N (becomes dinv in place)
    float* y     = deg + N;              // 2N (becomes gp after mlp)
    float* a     = y + 2 * (size_t)N;    // 2N
    float* out   = (float*)d_out;

    hipMemsetAsync(cnt, 0, MAX_NBUCK * sizeof(u32), stream);

    hist_kernel   <<<1024, 256, 0, stream>>>(dst, cnt, E, nbuck);
    scan_kernel   <<<1, MAX_NBUCK, 0, stream>>>(cnt, offsets, cursor, nbuck);
    scatter_kernel<<<(E + SCATTER_CHUNK - 1) / SCATTER_CHUNK, 256, 0, stream>>>(
        src, dst, cursor, sorted, E, nbuck);
    deg_kernel    <<<nbuck, BUCKET_SIZE, 0, stream>>>(sorted, offsets, deg, N);
    dinv_y_kernel <<<(N + 255) / 256, 256, 0, stream>>>(deg, x, (float2*)y, N);
    agg1_kernel   <<<nbuck, BUCKET_SIZE, 0, stream>>>(sorted, offsets, (const float2*)y,
                                                      deg, (float2*)a, N);
    mlp_kernel    <<<(N + 255) / 256, 256, 0, stream>>>(deg, (const float2*)a, W1, b1, W2,
                                                        (float2*)y /*gp*/, N);
    agg2_kernel   <<<nbuck, BUCKET_SIZE, 0, stream>>>(sorted, offsets, (const float2*)y,
                                                      deg, b2, (float2*)out, N);
}

// Round 9
// 292.605 us; speedup vs baseline: 5.4249x; 1.2726x over previous
//
#include <hip/hip_runtime.h>

// GCN 2-layer, atomic-free aggregation (counting-sort by dst bucket + LDS
// accumulation; global fp32 atomics are EA-bound on gfx950, eliminated r5).
// Round-9: DETERMINISTIC partition sort. r6/r8 showed intermittent replay
// divergence (~1 lost edge) with the global-cursor reservation scatter; the
// race could not be pinned by inspection, so all cross-block runtime
// interaction is removed: per-chunk histograms -> per-bucket scan over chunks
// -> scatter with precomputed read-only bases. No global atomics, no memset,
// every intermediate is a pure function of the inputs. deg/dinv_y/agg/mlp are
// byte-identical to round-5's replay-proven versions.

typedef unsigned int u32;

#define BUCKET_BITS 9
#define BUCKET_SIZE (1 << BUCKET_BITS)   // 512 nodes per bucket
#define MAX_NBUCK 512                    // supports N <= 262144
#define SCHUNK 16384                     // edges per scatter chunk
#define STHREADS 512                     // requires NB = ceil(E/SCHUNK) <= 512

// ---- Phase A: deterministic counting sort of edges by dst bucket ----

// K1: per-chunk bucket histogram -> part[c*nbuck + j]  (no global atomics)
__global__ void part_hist_kernel(const int* __restrict__ dst, u32* __restrict__ part,
                                 int E, int nbuck) {
    __shared__ u32 h[MAX_NBUCK];
    int t = threadIdx.x, c = blockIdx.x;
    for (int j = t; j < nbuck; j += STHREADS) h[j] = 0;
    __syncthreads();
    int start = c * SCHUNK, end = min(start + SCHUNK, E);
    for (int i = start + t; i < end; i += STHREADS)
        atomicAdd(&h[((u32)dst[i]) >> BUCKET_BITS], 1u);
    __syncthreads();
    for (int j = t; j < nbuck; j += STHREADS)
        part[(size_t)c * nbuck + j] = h[j];
}

// K2: per-bucket exclusive prefix across chunks (in place); totals -> cnt[j].
// One block per bucket, Hillis-Steele over 512 slots (NB <= 512).
__global__ void colscan_kernel(u32* __restrict__ part, u32* __restrict__ cnt,
                               int NB, int nbuck) {
    __shared__ u32 s[512];
    int t = threadIdx.x, j = blockIdx.x;  // j < nbuck
    u32 v = (t < NB) ? part[(size_t)t * nbuck + j] : 0u;
    s[t] = v;
    for (int o = 1; o < 512; o <<= 1) {
        __syncthreads();
        u32 u = (t >= o) ? s[t - o] : 0u;
        __syncthreads();
        s[t] += u;
    }
    __syncthreads();
    if (t < NB) part[(size_t)t * nbuck + j] = s[t] - v;  // exclusive prefix
    if (t == 511) cnt[j] = s[511];                       // bucket total
}

// K3: exclusive scan of bucket totals -> offsets[0..nbuck]
__global__ void offsets_kernel(const u32* __restrict__ cnt, u32* __restrict__ offsets,
                               int nbuck) {
    __shared__ u32 s[MAX_NBUCK];
    int t = threadIdx.x;  // 512
    u32 v = (t < nbuck) ? cnt[t] : 0u;
    s[t] = v;
    for (int o = 1; o < MAX_NBUCK; o <<= 1) {
        __syncthreads();
        u32 u = (t >= o) ? s[t - o] : 0u;
        __syncthreads();
        s[t] += u;
    }
    __syncthreads();
    if (t < nbuck) offsets[t + 1] = s[t];  // inclusive -> offsets[j+1]
    if (t == 0) offsets[0] = 0;
}

// K4: scatter with precomputed read-only bases (no cross-block interaction)
__global__ void scatter_kernel(const int* __restrict__ src, const int* __restrict__ dst,
                               const u32* __restrict__ part, const u32* __restrict__ offsets,
                               u32* __restrict__ sorted, int E, int nbuck) {
    __shared__ u32 base[MAX_NBUCK];
    __shared__ u32 rank[MAX_NBUCK];
    int t = threadIdx.x, c = blockIdx.x;
    for (int j = t; j < nbuck; j += STHREADS) {
        base[j] = offsets[j] + part[(size_t)c * nbuck + j];
        rank[j] = 0;
    }
    __syncthreads();
    int start = c * SCHUNK, end = min(start + SCHUNK, E);
    for (int i = start + t; i < end; i += STHREADS) {
        u32 d = (u32)dst[i];
        u32 b = d >> BUCKET_BITS;
        u32 pos = base[b] + atomicAdd(&rank[b], 1u);
        sorted[pos] = ((u32)src[i] << BUCKET_BITS) | (d & (BUCKET_SIZE - 1));
    }
}

// ---- Phase B: bucketed LDS aggregation (byte-identical to round 5) ----

__global__ void deg_kernel(const u32* __restrict__ sorted, const u32* __restrict__ offsets,
                           float* __restrict__ deg, int N) {
    __shared__ float cnt[BUCKET_SIZE];
    int t = threadIdx.x;  // 512
    cnt[t] = 0.f;
    __syncthreads();
    int b = blockIdx.x;
    u32 e1 = offsets[b + 1];
    for (u32 i = offsets[b] + t; i < e1; i += blockDim.x)
        atomicAdd(&cnt[sorted[i] & (BUCKET_SIZE - 1)], 1.0f);
    __syncthreads();
    int node = (b << BUCKET_BITS) + t;
    if (node < N) deg[node] = cnt[t];
}

__global__ void dinv_y_kernel(float* __restrict__ deg /*in-place -> dinv*/,
                              const float2* __restrict__ x, float2* __restrict__ y, int N) {
    int i = blockIdx.x * blockDim.x + threadIdx.x;
    if (i >= N) return;
    float di = rsqrtf(deg[i] + 1.0f);  // +1 self-loop, always > 0
    deg[i] = di;
    float2 xv = x[i];
    y[i] = make_float2(di * xv.x, di * xv.y);
}

// a[d] = dinv[d] * (sum_{s->d} y[s] + y[d])
__global__ void agg1_kernel(const u32* __restrict__ sorted, const u32* __restrict__ offsets,
                            const float2* __restrict__ y, const float* __restrict__ dinv,
                            float2* __restrict__ a, int N) {
    __shared__ float accx[BUCKET_SIZE];
    __shared__ float accy[BUCKET_SIZE];
    int t = threadIdx.x;  // 512
    accx[t] = 0.f;
    accy[t] = 0.f;
    __syncthreads();
    int b = blockIdx.x;
    u32 e1 = offsets[b + 1];
#pragma unroll 4
    for (u32 i = offsets[b] + t; i < e1; i += blockDim.x) {
        u32 e = sorted[i];
        float2 v = y[e >> BUCKET_BITS];
        u32 ld = e & (BUCKET_SIZE - 1);
        atomicAdd(&accx[ld], v.x);
        atomicAdd(&accy[ld], v.y);
    }
    __syncthreads();
    int node = (b << BUCKET_BITS) + t;
    if (node < N) {
        float2 yv = y[node];
        float di = dinv[node];
        a[node] = make_float2(di * (accx[t] + yv.x), di * (accy[t] + yv.y));
    }
}

// h = relu(a W1 + b1); gp = dinv * (h W2)   (gp aliases the y buffer)
__global__ void mlp_kernel(const float* __restrict__ dinv, const float2* __restrict__ a,
                           const float* __restrict__ W1, const float* __restrict__ b1,
                           const float* __restrict__ W2, float2* __restrict__ gp, int N) {
    int i = blockIdx.x * blockDim.x + threadIdx.x;
    if (i >= N) return;
    float2 av = a[i];
    float g0 = 0.f, g1 = 0.f;
#pragma unroll
    for (int j = 0; j < 16; ++j) {
        float h = fmaf(av.x, W1[j], fmaf(av.y, W1[16 + j], b1[j]));
        h = fmaxf(h, 0.f);
        g0 = fmaf(h, W2[2 * j], g0);
        g1 = fmaf(h, W2[2 * j + 1], g1);
    }
    float di = dinv[i];
    gp[i] = make_float2(di * g0, di * g1);
}

// out[d] = dinv[d] * (sum_{s->d} gp[s] + gp[d]) + b2
__global__ void agg2_kernel(const u32* __restrict__ sorted, const u32* __restrict__ offsets,
                            const float2* __restrict__ gp, const float* __restrict__ dinv,
                            const float* __restrict__ b2, float2* __restrict__ out, int N) {
    __shared__ float accx[BUCKET_SIZE];
    __shared__ float accy[BUCKET_SIZE];
    int t = threadIdx.x;  // 512
    accx[t] = 0.f;
    accy[t] = 0.f;
    __syncthreads();
    int b = blockIdx.x;
    u32 e1 = offsets[b + 1];
#pragma unroll 4
    for (u32 i = offsets[b] + t; i < e1; i += blockDim.x) {
        u32 e = sorted[i];
        float2 v = gp[e >> BUCKET_BITS];
        u32 ld = e & (BUCKET_SIZE - 1);
        atomicAdd(&accx[ld], v.x);
        atomicAdd(&accy[ld], v.y);
    }
    __syncthreads();
    int node = (b << BUCKET_BITS) + t;
    if (node < N) {
        float2 gv = gp[node];
        float di = dinv[node];
        out[node] = make_float2(fmaf(di, accx[t] + gv.x, b2[0]),
                                fmaf(di, accy[t] + gv.y, b2[1]));
    }
}

extern "C" void kernel_launch(void* const* d_in, const int* in_sizes, int n_in,
                              void* d_out, int out_size, void* d_ws, size_t ws_size,
                              hipStream_t stream) {
    const float2* x  = (const float2*)d_in[0];
    const int*    ei = (const int*)d_in[1];   // [2, E]: src row then dst row
    const float*  W1 = (const float*)d_in[2];
    const float*  b1 = (const float*)d_in[3];
    const float*  W2 = (const float*)d_in[4];
    const float*  b2 = (const float*)d_in[5];

    const int N = in_sizes[0] / 2;
    const int E = in_sizes[1] / 2;
    const int* src = ei;
    const int* dst = ei + E;
    const int nbuck = (N + BUCKET_SIZE - 1) >> BUCKET_BITS;   // 391
    const int NB    = (E + SCHUNK - 1) / SCHUNK;              // 391 (<= 512)

    u32* part    = (u32*)d_ws;                        // NB*nbuck  (~612 KB)
    u32* cnt     = part + (size_t)NB * nbuck;         // nbuck
    u32* offsets = cnt + MAX_NBUCK;                   // nbuck+1
    u32* sorted  = offsets + MAX_NBUCK + 1;           // E
    float* deg   = (float*)(sorted + E);              // N (-> dinv in place)
    float* y     = deg + N;                           // 2N (-> gp after mlp)
    float* a     = y + 2 * (size_t)N;                 // 2N
    float* out   = (float*)d_out;

    part_hist_kernel<<<NB, STHREADS, 0, stream>>>(dst, part, E, nbuck);
    colscan_kernel  <<<nbuck, 512, 0, stream>>>(part, cnt, NB, nbuck);
    offsets_kernel  <<<1, MAX_NBUCK, 0, stream>>>(cnt, offsets, nbuck);
    scatter_kernel  <<<NB, STHREADS, 0, stream>>>(src, dst, part, offsets, sorted, E, nbuck);
    deg_kernel      <<<nbuck, BUCKET_SIZE, 0, stream>>>(sorted, offsets, deg, N);
    dinv_y_kernel   <<<(N + 255) / 256, 256, 0, stream>>>(deg, x, (float2*)y, N);
    agg1_kernel     <<<nbuck, BUCKET_SIZE, 0, stream>>>(sorted, offsets, (const float2*)y,
                                                        deg, (float2*)a, N);
    mlp_kernel      <<<(N + 255) / 256, 256, 0, stream>>>(deg, (const float2*)a, W1, b1, W2,
                                                          (float2*)y /*gp*/, N);
    agg2_kernel     <<<nbuck, BUCKET_SIZE, 0, stream>>>(sorted, offsets, (const float2*)y,
                                                        deg, b2, (float2*)out, N);
}

// Round 10
// 274.148 us; speedup vs baseline: 5.7901x; 1.0673x over previous
//
#include <hip/hip_runtime.h>

// GCN 2-layer, deterministic sort + LDS aggregation (gfx950).
// History: global fp32 atomics are EA write-through (~20G/s) -> eliminated (r5).
// Cursor-reservation scatter raced on graph replay (r6/r8); deterministic
// partition sort (r9) is replay-stable. Round-10: (1) LDS-reorder scatter with
// PRECOMPUTED bases (no cross-block mutable state) so stream-out stores are
// coalesced -> kill the remaining 4x write amplification (100MB for 25.6MB);
// (2) fuse dinv+y into deg; (3) fuse MLP into agg1 epilogue.

typedef unsigned int u32;
typedef unsigned short u16;

#define BUCKET_BITS 9
#define BUCKET_SIZE (1 << BUCKET_BITS)   // 512 nodes per bucket
#define MAX_NBUCK 512                    // supports N <= 262144
#define PCHUNK 8192                      // edges per partition chunk
#define STHREADS 512
#define MAX_NB 1024                      // supports E <= 8.4M

// K1: per-chunk bucket histogram -> part[c*nbuck + j]  (no global atomics)
__global__ void part_hist_kernel(const int* __restrict__ dst, u32* __restrict__ part,
                                 int E, int nbuck) {
    __shared__ u32 h[MAX_NBUCK];
    int t = threadIdx.x, c = blockIdx.x;
    h[t] = 0;
    __syncthreads();
    int start = c * PCHUNK, end = min(start + PCHUNK, E);
    for (int i = start + t; i < end; i += STHREADS)
        atomicAdd(&h[((u32)dst[i]) >> BUCKET_BITS], 1u);
    __syncthreads();
    for (int j = t; j < nbuck; j += STHREADS)
        part[(size_t)c * nbuck + j] = h[j];
}

// K2: per-bucket exclusive prefix across chunks (in place); totals -> cnt[j].
__global__ void colscan_kernel(u32* __restrict__ part, u32* __restrict__ cnt,
                               int NB, int nbuck) {
    __shared__ u32 s[MAX_NB];
    int t = threadIdx.x, j = blockIdx.x;  // 1024 threads, j < nbuck
    u32 v = (t < NB) ? part[(size_t)t * nbuck + j] : 0u;
    s[t] = v;
    for (int o = 1; o < MAX_NB; o <<= 1) {
        __syncthreads();
        u32 u = (t >= o) ? s[t - o] : 0u;
        __syncthreads();
        s[t] += u;
    }
    __syncthreads();
    if (t < NB) part[(size_t)t * nbuck + j] = s[t] - v;  // exclusive prefix
    if (t == MAX_NB - 1) cnt[j] = s[MAX_NB - 1];         // bucket total
}

// K3: exclusive scan of bucket totals -> offsets[0..nbuck]
__global__ void offsets_kernel(const u32* __restrict__ cnt, u32* __restrict__ offsets,
                               int nbuck) {
    __shared__ u32 s[MAX_NBUCK];
    int t = threadIdx.x;  // 512
    u32 v = (t < nbuck) ? cnt[t] : 0u;
    s[t] = v;
    for (int o = 1; o < MAX_NBUCK; o <<= 1) {
        __syncthreads();
        u32 u = (t >= o) ? s[t - o] : 0u;
        __syncthreads();
        s[t] += u;
    }
    __syncthreads();
    if (t < nbuck) offsets[t + 1] = s[t];
    if (t == 0) offsets[0] = 0;
}

// K4: LDS-reorder scatter. Bases precomputed (read-only part/offsets); the
// chunk is placed bucket-ordered into LDS, then streamed out so consecutive
// threads write consecutive global addresses (full-line write combining).
__global__ void __launch_bounds__(STHREADS)
scatter_kernel(const int* __restrict__ src, const int* __restrict__ dst,
               const u32* __restrict__ part, const u32* __restrict__ offsets,
               u32* __restrict__ sorted, int E, int nbuck) {
    __shared__ u32 pk[PCHUNK];        // 32 KB packed edges, bucket-ordered
    __shared__ u16 bk[PCHUNK];        // 16 KB bucket id per slot
    __shared__ u32 hist[MAX_NBUCK];   // counts -> local exclusive base
    __shared__ u32 scr[MAX_NBUCK];    // scan workspace -> rank counters
    __shared__ u32 dadj[MAX_NBUCK];   // global_base - local_base
    int t = threadIdx.x, c = blockIdx.x;
    int start = c * PCHUNK, end = min(start + PCHUNK, E);
    int cntE = end - start;

    hist[t] = 0;
    __syncthreads();
    for (int i = start + t; i < end; i += STHREADS)
        atomicAdd(&hist[((u32)dst[i]) >> BUCKET_BITS], 1u);
    __syncthreads();
    // local exclusive scan (Hillis-Steele over 512)
    u32 v = hist[t];
    scr[t] = v;
    for (int o = 1; o < MAX_NBUCK; o <<= 1) {
        __syncthreads();
        u32 u = (t >= o) ? scr[t - o] : 0u;
        __syncthreads();
        scr[t] += u;
    }
    __syncthreads();
    // own-slot accesses only between the barriers below: no cross-thread hazard
    u32 lb = scr[t] - v;
    hist[t] = lb;          // reuse hist as local base
    if (t < nbuck)
        dadj[t] = offsets[t] + part[(size_t)c * nbuck + t] - lb;
    scr[t] = 0;            // reuse scr as rank counters
    __syncthreads();
    // place edges bucket-ordered into LDS (unique slots; order within a run
    // is nondeterministic but that only permutes float-add order downstream)
    for (int i = start + t; i < end; i += STHREADS) {
        u32 d = (u32)dst[i];
        u32 b = d >> BUCKET_BITS;
        u32 p = hist[b] + atomicAdd(&scr[b], 1u);
        pk[p] = ((u32)src[i] << BUCKET_BITS) | (d & (BUCKET_SIZE - 1));
        bk[p] = (u16)b;
    }
    __syncthreads();
    // coalesced stream-out: global addr = dadj[bucket] + local slot
    for (int i = t; i < cntE; i += STHREADS)
        sorted[dadj[bk[i]] + i] = pk[i];
}

// K5: per-node degree (LDS count) fused with dinv = rsqrt(deg+1), y = dinv*x
__global__ void deg_y_kernel(const u32* __restrict__ sorted, const u32* __restrict__ offsets,
                             const float2* __restrict__ x,
                             float* __restrict__ dinv, float2* __restrict__ y, int N) {
    __shared__ float cnt_s[BUCKET_SIZE];
    int t = threadIdx.x;  // 512
    cnt_s[t] = 0.f;
    __syncthreads();
    int b = blockIdx.x;
    u32 e1 = offsets[b + 1];
    for (u32 i = offsets[b] + t; i < e1; i += BUCKET_SIZE)
        atomicAdd(&cnt_s[sorted[i] & (BUCKET_SIZE - 1)], 1.0f);
    __syncthreads();
    int node = (b << BUCKET_BITS) + t;
    if (node < N) {
        float di = rsqrtf(cnt_s[t] + 1.0f);  // +1 self-loop, always > 0
        dinv[node] = di;
        float2 xv = x[node];
        y[node] = make_float2(di * xv.x, di * xv.y);
    }
}

// K6: layer-1 aggregation + fused 2->16->2 MLP epilogue.
// a = dinv[d]*(sum y[s] + y[d]); h = relu(a W1 + b1); gp = dinv * (h W2)
__global__ void agg1_mlp_kernel(const u32* __restrict__ sorted, const u32* __restrict__ offsets,
                                const float2* __restrict__ y, const float* __restrict__ dinv,
                                const float* __restrict__ W1, const float* __restrict__ b1,
                                const float* __restrict__ W2,
                                float2* __restrict__ gp, int N) {
    __shared__ float accx[BUCKET_SIZE];
    __shared__ float accy[BUCKET_SIZE];
    int t = threadIdx.x;  // 512
    accx[t] = 0.f;
    accy[t] = 0.f;
    __syncthreads();
    int b = blockIdx.x;
    u32 e1 = offsets[b + 1];
#pragma unroll 4
    for (u32 i = offsets[b] + t; i < e1; i += BUCKET_SIZE) {
        u32 e = sorted[i];
        float2 v = y[e >> BUCKET_BITS];
        u32 ld = e & (BUCKET_SIZE - 1);
        atomicAdd(&accx[ld], v.x);
        atomicAdd(&accy[ld], v.y);
    }
    __syncthreads();
    int node = (b << BUCKET_BITS) + t;
    if (node < N) {
        float di = dinv[node];
        float2 yv = y[node];
        float ax = di * (accx[t] + yv.x);
        float ay = di * (accy[t] + yv.y);
        float g0 = 0.f, g1 = 0.f;
#pragma unroll
        for (int j = 0; j < 16; ++j) {
            float h = fmaf(ax, W1[j], fmaf(ay, W1[16 + j], b1[j]));
            h = fmaxf(h, 0.f);
            g0 = fmaf(h, W2[2 * j], g0);
            g1 = fmaf(h, W2[2 * j + 1], g1);
        }
        gp[node] = make_float2(di * g0, di * g1);
    }
}

// K7: layer-2 aggregation: out = dinv[d]*(sum gp[s] + gp[d]) + b2
__global__ void agg2_kernel(const u32* __restrict__ sorted, const u32* __restrict__ offsets,
                            const float2* __restrict__ gp, const float* __restrict__ dinv,
                            const float* __restrict__ b2, float2* __restrict__ out, int N) {
    __shared__ float accx[BUCKET_SIZE];
    __shared__ float accy[BUCKET_SIZE];
    int t = threadIdx.x;  // 512
    accx[t] = 0.f;
    accy[t] = 0.f;
    __syncthreads();
    int b = blockIdx.x;
    u32 e1 = offsets[b + 1];
#pragma unroll 4
    for (u32 i = offsets[b] + t; i < e1; i += BUCKET_SIZE) {
        u32 e = sorted[i];
        float2 v = gp[e >> BUCKET_BITS];
        u32 ld = e & (BUCKET_SIZE - 1);
        atomicAdd(&accx[ld], v.x);
        atomicAdd(&accy[ld], v.y);
    }
    __syncthreads();
    int node = (b << BUCKET_BITS) + t;
    if (node < N) {
        float2 gv = gp[node];
        float di = dinv[node];
        out[node] = make_float2(fmaf(di, accx[t] + gv.x, b2[0]),
                                fmaf(di, accy[t] + gv.y, b2[1]));
    }
}

extern "C" void kernel_launch(void* const* d_in, const int* in_sizes, int n_in,
                              void* d_out, int out_size, void* d_ws, size_t ws_size,
                              hipStream_t stream) {
    const float2* x  = (const float2*)d_in[0];
    const int*    ei = (const int*)d_in[1];   // [2, E]: src row then dst row
    const float*  W1 = (const float*)d_in[2];
    const float*  b1 = (const float*)d_in[3];
    const float*  W2 = (const float*)d_in[4];
    const float*  b2 = (const float*)d_in[5];

    const int N = in_sizes[0] / 2;
    const int E = in_sizes[1] / 2;
    const int* src = ei;
    const int* dst = ei + E;
    const int nbuck = (N + BUCKET_SIZE - 1) >> BUCKET_BITS;   // 391
    const int NB    = (E + PCHUNK - 1) / PCHUNK;              // 782 (<= 1024)

    // Workspace. `part` (NB*nbuck u32, ~1.22MB <= 2N floats) ALIASES `y`:
    // part's last reader is scatter_kernel; y's first writer is deg_y_kernel,
    // strictly later on the same stream -> safe, keeps ws in proven budget.
    u32* sorted   = (u32*)d_ws;                       // E
    float* dinv   = (float*)(sorted + E);             // N
    float* y      = dinv + N;                         // 2N
    float* gp     = y + 2 * (size_t)N;                // 2N
    u32* cnt      = (u32*)(gp + 2 * (size_t)N);       // 512
    u32* offsets  = cnt + MAX_NBUCK;                  // nbuck+1
    u32* part     = (u32*)y;                          // NB*nbuck alias
    float2* out   = (float2*)d_out;

    part_hist_kernel<<<NB, STHREADS, 0, stream>>>(dst, part, E, nbuck);
    colscan_kernel  <<<nbuck, MAX_NB, 0, stream>>>(part, cnt, NB, nbuck);
    offsets_kernel  <<<1, MAX_NBUCK, 0, stream>>>(cnt, offsets, nbuck);
    scatter_kernel  <<<NB, STHREADS, 0, stream>>>(src, dst, part, offsets, sorted, E, nbuck);
    deg_y_kernel    <<<nbuck, BUCKET_SIZE, 0, stream>>>(sorted, offsets, x, dinv,
                                                        (float2*)y, N);
    agg1_mlp_kernel <<<nbuck, BUCKET_SIZE, 0, stream>>>(sorted, offsets, (const float2*)y,
                                                        dinv, W1, b1, W2, (float2*)gp, N);
    agg2_kernel     <<<nbuck, BUCKET_SIZE, 0, stream>>>(sorted, offsets, (const float2*)gp,
                                                        dinv, b2, out, N);
}

// Round 11
// 226.100 us; speedup vs baseline: 7.0206x; 1.2125x over previous
//
#include <hip/hip_runtime.h>

// GCN 2-layer, deterministic sort + LDS aggregation (gfx950).
// History: global fp32 atomics are EA write-through -> eliminated (r5);
// cursor-reservation scatter raced on replay (r6/r8) -> deterministic
// partition sort (r9); LDS-reorder scatter + fusions (r10, 274us).
// Round-11: bucket edge passes were latency-bound at 24% occupancy (89us with
// all counters idle: 391 blocks, 1.5/CU, serial 32-edge loops on ~225cy L2
// gathers). SPLIT=4 blocks per bucket write LDS partials (pure-function,
// replay-deterministic); per-bucket combine kernels sum partials + epilogue.

typedef unsigned int u32;
typedef unsigned short u16;

#define BUCKET_BITS 9
#define BUCKET_SIZE (1 << BUCKET_BITS)   // 512 nodes per bucket
#define MAX_NBUCK 512                    // supports N <= 262144
#define PCHUNK 8192                      // edges per partition chunk
#define STHREADS 512
#define MAX_NB 1024                      // supports E <= 8.4M
#define SPLIT 4                          // split-blocks per bucket edge pass

// K1: per-chunk bucket histogram -> part[c*nbuck + j]  (no global atomics)
__global__ void part_hist_kernel(const int* __restrict__ dst, u32* __restrict__ part,
                                 int E, int nbuck) {
    __shared__ u32 h[MAX_NBUCK];
    int t = threadIdx.x, c = blockIdx.x;
    h[t] = 0;
    __syncthreads();
    int start = c * PCHUNK, end = min(start + PCHUNK, E);
    for (int i = start + t; i < end; i += STHREADS)
        atomicAdd(&h[((u32)dst[i]) >> BUCKET_BITS], 1u);
    __syncthreads();
    for (int j = t; j < nbuck; j += STHREADS)
        part[(size_t)c * nbuck + j] = h[j];
}

// K2: per-bucket exclusive prefix across chunks (in place); totals -> cnt[j]
__global__ void colscan_kernel(u32* __restrict__ part, u32* __restrict__ cnt,
                               int NB, int nbuck) {
    __shared__ u32 s[MAX_NB];
    int t = threadIdx.x, j = blockIdx.x;  // 1024 threads, j < nbuck
    u32 v = (t < NB) ? part[(size_t)t * nbuck + j] : 0u;
    s[t] = v;
    for (int o = 1; o < MAX_NB; o <<= 1) {
        __syncthreads();
        u32 u = (t >= o) ? s[t - o] : 0u;
        __syncthreads();
        s[t] += u;
    }
    __syncthreads();
    if (t < NB) part[(size_t)t * nbuck + j] = s[t] - v;  // exclusive prefix
    if (t == MAX_NB - 1) cnt[j] = s[MAX_NB - 1];         // bucket total
}

// K3: exclusive scan of bucket totals -> offsets[0..nbuck]
__global__ void offsets_kernel(const u32* __restrict__ cnt, u32* __restrict__ offsets,
                               int nbuck) {
    __shared__ u32 s[MAX_NBUCK];
    int t = threadIdx.x;  // 512
    u32 v = (t < nbuck) ? cnt[t] : 0u;
    s[t] = v;
    for (int o = 1; o < MAX_NBUCK; o <<= 1) {
        __syncthreads();
        u32 u = (t >= o) ? s[t - o] : 0u;
        __syncthreads();
        s[t] += u;
    }
    __syncthreads();
    if (t < nbuck) offsets[t + 1] = s[t];
    if (t == 0) offsets[0] = 0;
}

// K4: LDS-reorder scatter, precomputed bases (replay-proven in r10)
__global__ void __launch_bounds__(STHREADS)
scatter_kernel(const int* __restrict__ src, const int* __restrict__ dst,
               const u32* __restrict__ part, const u32* __restrict__ offsets,
               u32* __restrict__ sorted, int E, int nbuck) {
    __shared__ u32 pk[PCHUNK];
    __shared__ u16 bk[PCHUNK];
    __shared__ u32 hist[MAX_NBUCK];
    __shared__ u32 scr[MAX_NBUCK];
    __shared__ u32 dadj[MAX_NBUCK];
    int t = threadIdx.x, c = blockIdx.x;
    int start = c * PCHUNK, end = min(start + PCHUNK, E);
    int cntE = end - start;

    hist[t] = 0;
    __syncthreads();
    for (int i = start + t; i < end; i += STHREADS)
        atomicAdd(&hist[((u32)dst[i]) >> BUCKET_BITS], 1u);
    __syncthreads();
    u32 v = hist[t];
    scr[t] = v;
    for (int o = 1; o < MAX_NBUCK; o <<= 1) {
        __syncthreads();
        u32 u = (t >= o) ? scr[t - o] : 0u;
        __syncthreads();
        scr[t] += u;
    }
    __syncthreads();
    u32 lb = scr[t] - v;
    hist[t] = lb;
    if (t < nbuck)
        dadj[t] = offsets[t] + part[(size_t)c * nbuck + t] - lb;
    scr[t] = 0;
    __syncthreads();
    for (int i = start + t; i < end; i += STHREADS) {
        u32 d = (u32)dst[i];
        u32 b = d >> BUCKET_BITS;
        u32 p = hist[b] + atomicAdd(&scr[b], 1u);
        pk[p] = ((u32)src[i] << BUCKET_BITS) | (d & (BUCKET_SIZE - 1));
        bk[p] = (u16)b;
    }
    __syncthreads();
    for (int i = t; i < cntE; i += STHREADS)
        sorted[dadj[bk[i]] + i] = pk[i];
}

// K5: split degree count -> pdeg[block][t]  (pure function, coalesced write)
__global__ void deg_part_kernel(const u32* __restrict__ sorted, const u32* __restrict__ offsets,
                                u32* __restrict__ pdeg) {
    __shared__ u32 cnt_s[BUCKET_SIZE];
    int t = threadIdx.x;
    int b = blockIdx.x / SPLIT, s = blockIdx.x % SPLIT;
    cnt_s[t] = 0;
    __syncthreads();
    u32 e0 = offsets[b], len = offsets[b + 1] - e0;
    u32 lo = e0 + (len * s) / SPLIT, hi = e0 + (len * (s + 1)) / SPLIT;
#pragma unroll 4
    for (u32 i = lo + t; i < hi; i += BUCKET_SIZE)
        atomicAdd(&cnt_s[sorted[i] & (BUCKET_SIZE - 1)], 1u);
    __syncthreads();
    pdeg[(size_t)blockIdx.x * BUCKET_SIZE + t] = cnt_s[t];
}

// K6: combine degree partials; dinv = rsqrt(deg+1); y = dinv * x
__global__ void dinv_y_kernel(const u32* __restrict__ pdeg, const float2* __restrict__ x,
                              float* __restrict__ dinv, float2* __restrict__ y, int N) {
    int b = blockIdx.x, t = threadIdx.x;
    int node = (b << BUCKET_BITS) + t;
    if (node >= N) return;
    u32 d = 0;
#pragma unroll
    for (int s = 0; s < SPLIT; ++s)
        d += pdeg[((size_t)(b * SPLIT + s)) * BUCKET_SIZE + t];
    float di = rsqrtf((float)d + 1.0f);  // +1 self-loop, always > 0
    dinv[node] = di;
    float2 xv = x[node];
    y[node] = make_float2(di * xv.x, di * xv.y);
}

// K7 (used twice): split aggregation of 2-wide features -> pagg[block][t]
__global__ void aggp_kernel(const u32* __restrict__ sorted, const u32* __restrict__ offsets,
                            const float2* __restrict__ feat, float2* __restrict__ pagg) {
    __shared__ float accx[BUCKET_SIZE];
    __shared__ float accy[BUCKET_SIZE];
    int t = threadIdx.x;
    int b = blockIdx.x / SPLIT, s = blockIdx.x % SPLIT;
    accx[t] = 0.f;
    accy[t] = 0.f;
    __syncthreads();
    u32 e0 = offsets[b], len = offsets[b + 1] - e0;
    u32 lo = e0 + (len * s) / SPLIT, hi = e0 + (len * (s + 1)) / SPLIT;
#pragma unroll 4
    for (u32 i = lo + t; i < hi; i += BUCKET_SIZE) {
        u32 e = sorted[i];
        float2 v = feat[e >> BUCKET_BITS];
        u32 ld = e & (BUCKET_SIZE - 1);
        atomicAdd(&accx[ld], v.x);
        atomicAdd(&accy[ld], v.y);
    }
    __syncthreads();
    pagg[(size_t)blockIdx.x * BUCKET_SIZE + t] = make_float2(accx[t], accy[t]);
}

// K8: combine layer-1 partials + self-loop, then fused 2->16->2 MLP
__global__ void mlp_combine_kernel(const float2* __restrict__ pagg, const float2* __restrict__ y,
                                   const float* __restrict__ dinv,
                                   const float* __restrict__ W1, const float* __restrict__ b1,
                                   const float* __restrict__ W2,
                                   float2* __restrict__ gp, int N) {
    int b = blockIdx.x, t = threadIdx.x;
    int node = (b << BUCKET_BITS) + t;
    if (node >= N) return;
    float sx = 0.f, sy = 0.f;
#pragma unroll
    for (int s = 0; s < SPLIT; ++s) {
        float2 p = pagg[((size_t)(b * SPLIT + s)) * BUCKET_SIZE + t];
        sx += p.x; sy += p.y;
    }
    float di = dinv[node];
    float2 yv = y[node];
    float ax = di * (sx + yv.x);
    float ay = di * (sy + yv.y);
    float g0 = 0.f, g1 = 0.f;
#pragma unroll
    for (int j = 0; j < 16; ++j) {
        float h = fmaf(ax, W1[j], fmaf(ay, W1[16 + j], b1[j]));
        h = fmaxf(h, 0.f);
        g0 = fmaf(h, W2[2 * j], g0);
        g1 = fmaf(h, W2[2 * j + 1], g1);
    }
    gp[node] = make_float2(di * g0, di * g1);
}

// K9: combine layer-2 partials + self-loop + bias -> out
__global__ void final_combine_kernel(const float2* __restrict__ pagg, const float2* __restrict__ gp,
                                     const float* __restrict__ dinv, const float* __restrict__ b2,
                                     float2* __restrict__ out, int N) {
    int b = blockIdx.x, t = threadIdx.x;
    int node = (b << BUCKET_BITS) + t;
    if (node >= N) return;
    float sx = 0.f, sy = 0.f;
#pragma unroll
    for (int s = 0; s < SPLIT; ++s) {
        float2 p = pagg[((size_t)(b * SPLIT + s)) * BUCKET_SIZE + t];
        sx += p.x; sy += p.y;
    }
    float di = dinv[node];
    float2 gv = gp[node];
    out[node] = make_float2(fmaf(di, sx + gv.x, b2[0]),
                            fmaf(di, sy + gv.y, b2[1]));
}

extern "C" void kernel_launch(void* const* d_in, const int* in_sizes, int n_in,
                              void* d_out, int out_size, void* d_ws, size_t ws_size,
                              hipStream_t stream) {
    const float2* x  = (const float2*)d_in[0];
    const int*    ei = (const int*)d_in[1];   // [2, E]: src row then dst row
    const float*  W1 = (const float*)d_in[2];
    const float*  b1 = (const float*)d_in[3];
    const float*  W2 = (const float*)d_in[4];
    const float*  b2 = (const float*)d_in[5];

    const int N = in_sizes[0] / 2;
    const int E = in_sizes[1] / 2;
    const int* src = ei;
    const int* dst = ei + E;
    const int nbuck = (N + BUCKET_SIZE - 1) >> BUCKET_BITS;   // 391
    const int NB    = (E + PCHUNK - 1) / PCHUNK;              // 782 (<= 1024)

    // Workspace (lifetime-ordered aliases, all pure functions of inputs):
    //   part  (NB*nbuck u32, ~1.2MB) aliases y  : dead before deg_y writes y
    //   pdeg  (nbuck*SPLIT*512 u32)  aliases pagg: dead before aggp writes pagg
    //   pagg reused by both agg passes (combine1 reads before agg2 rewrites)
    u32* sorted   = (u32*)d_ws;                               // E
    float* dinv   = (float*)(sorted + E);                     // N
    float* y      = dinv + N;                                 // 2N
    float* gp     = y + 2 * (size_t)N;                        // 2N
    float2* pagg  = (float2*)(gp + 2 * (size_t)N);            // nbuck*SPLIT*512
    u32* pdeg     = (u32*)pagg;                               // alias (half size)
    u32* cnt      = (u32*)(pagg + (size_t)nbuck * SPLIT * BUCKET_SIZE); // 512
    u32* offsets  = cnt + MAX_NBUCK;                          // nbuck+1
    u32* part     = (u32*)y;                                  // alias
    float2* out   = (float2*)d_out;

    part_hist_kernel  <<<NB, STHREADS, 0, stream>>>(dst, part, E, nbuck);
    colscan_kernel    <<<nbuck, MAX_NB, 0, stream>>>(part, cnt, NB, nbuck);
    offsets_kernel    <<<1, MAX_NBUCK, 0, stream>>>(cnt, offsets, nbuck);
    scatter_kernel    <<<NB, STHREADS, 0, stream>>>(src, dst, part, offsets, sorted, E, nbuck);
    deg_part_kernel   <<<nbuck * SPLIT, BUCKET_SIZE, 0, stream>>>(sorted, offsets, pdeg);
    dinv_y_kernel     <<<nbuck, BUCKET_SIZE, 0, stream>>>(pdeg, x, dinv, (float2*)y, N);
    aggp_kernel       <<<nbuck * SPLIT, BUCKET_SIZE, 0, stream>>>(sorted, offsets,
                                                                  (const float2*)y, pagg);
    mlp_combine_kernel<<<nbuck, BUCKET_SIZE, 0, stream>>>(pagg, (const float2*)y, dinv,
                                                          W1, b1, W2, (float2*)gp, N);
    aggp_kernel       <<<nbuck * SPLIT, BUCKET_SIZE, 0, stream>>>(sorted, offsets,
                                                                  (const float2*)gp, pagg);
    final_combine_kernel<<<nbuck, BUCKET_SIZE, 0, stream>>>(pagg, (const float2*)gp, dinv,
                                                            b2, out, N);
}